// Round 3
// baseline (148.397 us; speedup 1.0000x reference)
//
#include <hip/hip_runtime.h>
#include <hip/hip_bf16.h>

typedef __attribute__((ext_vector_type(8))) short short8;
typedef __attribute__((ext_vector_type(4))) float f32x4;

__device__ __forceinline__ unsigned short f32_bf16(float f) {
  unsigned u = __float_as_uint(f);
  u += 0x7fffu + ((u >> 16) & 1u);  // round-to-nearest-even
  return (unsigned short)(u >> 16);
}

// HW packed f32->bf16 (RNE): dst[15:0]=bf16(lo), dst[31:16]=bf16(hi)
__device__ __forceinline__ unsigned cvt_pk_bf16(float lo, float hi) {
  unsigned r;
  asm("v_cvt_pk_bf16_f32 %0, %1, %2" : "=v"(r) : "v"(lo), "v"(hi));
  return r;
}

__device__ __forceinline__ short8 cvt8(float4 v0, float4 v1) {
  union { unsigned u[4]; short8 s; } f;
  f.u[0] = cvt_pk_bf16(v0.x, v0.y);
  f.u[1] = cvt_pk_bf16(v0.z, v0.w);
  f.u[2] = cvt_pk_bf16(v1.x, v1.y);
  f.u[3] = cvt_pk_bf16(v1.z, v1.w);
  return f.s;
}

// unpack two bf16 pairs, add U+V (bias pre-folded into U), relu, repack
__device__ __forceinline__ unsigned addrelu2(unsigned uw, unsigned vw) {
  float ulo = __uint_as_float(uw << 16);
  float uhi = __uint_as_float(uw & 0xffff0000u);
  float vlo = __uint_as_float(vw << 16);
  float vhi = __uint_as_float(vw & 0xffff0000u);
  float slo = ulo + vlo; slo = slo > 0.f ? slo : 0.f;
  float shi = uhi + vhi; shi = shi > 0.f ? shi : 0.f;
  return cvt_pk_bf16(slo, shi);
}

// DPP row_shr:N add — lane 15 of each 16-lane row ends with the row sum.
template <int CTRL>
__device__ __forceinline__ float dpp_add(float x) {
  int y = __builtin_amdgcn_update_dpp(0, __float_as_int(x), CTRL, 0xf, 0xf, true);
  return x + __int_as_float(y);
}
__device__ __forceinline__ float row_sum16(float x) {
  x = dpp_add<0x118>(x);
  x = dpp_add<0x114>(x);
  x = dpp_add<0x112>(x);
  x = dpp_add<0x111>(x);
  return x;
}

// ---- pass 1: UV[n] = [ Z[n]·W1a + b1 , Z[n]·W1b ] in bf16 (256 B/node) -----
// Dense GEMM M=nNodes, N=128, K=128 on 16x16x32 MFMA. W1 B-fragments staged in
// LDS with slot(t, col=l15) = feature l15*8+t, so each lane's 8 outputs are
// feature-contiguous -> one uint4 store/row. b1 is folded into the U half
// (features 0..63) here so lp_edge needn't touch it (frees 16 VGPR there).
__global__ __launch_bounds__(256, 2) void uv_kernel(
    const float* __restrict__ z, const float* __restrict__ W1,
    const float* __restrict__ b1,
    unsigned short* __restrict__ uv, int nNodes) {
  __shared__ unsigned short w1l[32 * 64 * 8];  // 32 KB
  const int tid = threadIdx.x;
  const int wv  = tid >> 6;
  const int l   = tid & 63;
  const int l15 = l & 15;
  const int q   = l >> 4;

#pragma unroll
  for (int pp = 0; pp < 8; ++pp) {
    int p = wv * 8 + pp;       // p = c*8 + t
    int c = p >> 3, t = p & 7;
    short8 f;
#pragma unroll
    for (int j = 0; j < 8; ++j) {
      int k = c * 32 + q * 8 + j;
      int n = l15 * 8 + t;
      int row = (n < 64) ? k : (k + 128);
      f[j] = (short)f32_bf16(W1[row * 64 + (n & 63)]);
    }
    *(short8*)(w1l + (p * 64 + l) * 8) = f;
  }
  // bias for this lane's 8 features (n = l15*8+t); V half (l15>=8) gets 0
  float b1v[8];
  const int bbase = (l15 & 7) * 8;
#pragma unroll
  for (int j = 0; j < 8; ++j) b1v[j] = (l15 < 8) ? b1[bbase + j] : 0.f;
  __syncthreads();

  const int nTiles = (nNodes + 15) >> 4;
  const int stride = gridDim.x * 4;
  for (int tile = blockIdx.x * 4 + wv; tile < nTiles; tile += stride) {
    int node = tile * 16 + l15;
    node = node < nNodes ? node : nNodes - 1;
    const float* zr = z + (size_t)node * 128;
    short8 a[4];
#pragma unroll
    for (int c = 0; c < 4; ++c) {
      int off = c * 32 + q * 8;
      a[c] = cvt8(*(const float4*)(zr + off), *(const float4*)(zr + off + 4));
    }
    f32x4 acc[8];
#pragma unroll
    for (int t = 0; t < 8; ++t) { acc[t][0] = 0.f; acc[t][1] = 0.f; acc[t][2] = 0.f; acc[t][3] = 0.f; }
#pragma unroll
    for (int c = 0; c < 4; ++c)
#pragma unroll
      for (int t = 0; t < 8; ++t) {
        short8 wf = *(const short8*)(w1l + ((c * 8 + t) * 64 + l) * 8);
        acc[t] = __builtin_amdgcn_mfma_f32_16x16x32_bf16(a[c], wf, acc[t], 0, 0, 0);
      }
    // D[row=q*4+r][col=l15], slot(t,l15) = feature l15*8+t -> natural order
#pragma unroll
    for (int r = 0; r < 4; ++r) {
      int no = tile * 16 + q * 4 + r;
      if (no < nNodes) {
        union { unsigned u[4]; uint4 u4; } pk;
#pragma unroll
        for (int t = 0; t < 4; ++t)
          pk.u[t] = cvt_pk_bf16(acc[2 * t][r] + b1v[2 * t], acc[2 * t + 1][r] + b1v[2 * t + 1]);
        *(uint4*)(uv + (size_t)no * 128 + l15 * 8) = pk.u4;
      }
    }
  }
}

// ---- pass 2: per-edge gather UV + relu-add + layers 2,3 + sigmoid -----------
// R3 theory: R2's VGPR=44 proved regalloc collapsed the software pipeline, and
// the VGPR+AGPR total in the 65..128 bucket capped residency at 4 waves/SIMD
// (measured 38% occupancy). Fix = TLP not ILP: drop the pipeline, fold b1 out
// (-16 regs), 32-bit saddr gather offsets (-4 regs, no 64-bit carry chains),
// and __launch_bounds__(256,8) to force total regs <= 64 -> 8 waves/SIMD.
__global__ __launch_bounds__(256, 8) void lp_edge(
    const unsigned short* __restrict__ uv, const int* __restrict__ ei,
    const float* __restrict__ W2, const float* __restrict__ b2,
    const float* __restrict__ W3, const float* __restrict__ b3,
    float* __restrict__ out, int nEdges) {
  const int tid = threadIdx.x;
  const int wv  = tid >> 6;
  const int l   = tid & 63;
  const int l15 = l & 15;
  const int q   = l >> 4;

  short8 w2f[2][2];
#pragma unroll
  for (int c = 0; c < 2; ++c)
#pragma unroll
    for (int t = 0; t < 2; ++t) {
      short8 f;
#pragma unroll
      for (int j = 0; j < 8; ++j)
        f[j] = (short)f32_bf16(W2[(c * 32 + q * 8 + j) * 32 + (t * 16 + l15)]);
      w2f[c][t] = f;
    }
  float bb2[2];
#pragma unroll
  for (int t = 0; t < 2; ++t) bb2[t] = b2[t * 16 + l15];
  const float w3a = W3[l15], w3b = W3[16 + l15], b3v = b3[0];

  const unsigned q16 = (unsigned)q * 16u;
  const unsigned char* __restrict__ ub = (const unsigned char*)uv;

  const int nIter = (nEdges + 15) >> 4;
  const int stride = gridDim.x * 4;
  const int it0 = blockIdx.x * 4 + wv;

  // index prefetch one iteration ahead (2 regs; cheap)
  int e0 = it0 * 16 + l15; e0 = e0 < nEdges ? e0 : nEdges - 1;
  int cS = __builtin_nontemporal_load(ei + e0);
  int cD = __builtin_nontemporal_load(ei + nEdges + e0);

  for (int iter = it0; iter < nIter; iter += stride) {
    // 32-bit voffsets -> saddr-form global loads (uv base stays in SGPRs)
    unsigned offU = ((unsigned)cS << 8) + q16;           // U half: bytes 0..127
    unsigned offV = ((unsigned)cD << 8) + 128u + q16;    // V half: bytes 128..255
    uint4 au0 = *(const uint4*)(ub + offU);
    uint4 au1 = *(const uint4*)(ub + offU + 64);
    uint4 av0 = *(const uint4*)(ub + offV);
    uint4 av1 = *(const uint4*)(ub + offV + 64);

    int nit = iter + stride;
    if (nit < nIter) {
      int e = nit * 16 + l15;
      e = e < nEdges ? e : nEdges - 1;
      cS = __builtin_nontemporal_load(ei + e);
      cD = __builtin_nontemporal_load(ei + nEdges + e);
    }

    // h1 fragments: relu(U' + V) (b1 pre-folded into U') — A-frag layout
    union { unsigned u[4]; short8 s; } f0, f1;
    f0.u[0] = addrelu2(au0.x, av0.x);
    f0.u[1] = addrelu2(au0.y, av0.y);
    f0.u[2] = addrelu2(au0.z, av0.z);
    f0.u[3] = addrelu2(au0.w, av0.w);
    f1.u[0] = addrelu2(au1.x, av1.x);
    f1.u[1] = addrelu2(au1.y, av1.y);
    f1.u[2] = addrelu2(au1.z, av1.z);
    f1.u[3] = addrelu2(au1.w, av1.w);

    // layer 2: [16,64] @ [64,32] + b2
    f32x4 acc2[2];
#pragma unroll
    for (int t = 0; t < 2; ++t) {
      acc2[t][0] = bb2[t]; acc2[t][1] = bb2[t]; acc2[t][2] = bb2[t]; acc2[t][3] = bb2[t];
    }
#pragma unroll
    for (int t = 0; t < 2; ++t) {
      acc2[t] = __builtin_amdgcn_mfma_f32_16x16x32_bf16(f0.s, w2f[0][t], acc2[t], 0, 0, 0);
      acc2[t] = __builtin_amdgcn_mfma_f32_16x16x32_bf16(f1.s, w2f[1][t], acc2[t], 0, 0, 0);
    }

    // layer 3: per-lane partial, DPP row-sum
    float p[4];
#pragma unroll
    for (int r = 0; r < 4; ++r) {
      float h0 = acc2[0][r]; h0 = h0 > 0.f ? h0 : 0.f;
      float h1v = acc2[1][r]; h1v = h1v > 0.f ? h1v : 0.f;
      p[r] = row_sum16(h0 * w3a + h1v * w3b);
    }

    if (l15 == 15) {
      int eb = iter * 16 + q * 4;
      f32x4 o;
      o[0] = 1.f / (1.f + __expf(-(p[0] + b3v)));
      o[1] = 1.f / (1.f + __expf(-(p[1] + b3v)));
      o[2] = 1.f / (1.f + __expf(-(p[2] + b3v)));
      o[3] = 1.f / (1.f + __expf(-(p[3] + b3v)));
      if (eb + 3 < nEdges) {
        __builtin_nontemporal_store(o, (f32x4*)(out + eb));
      } else {
        if (eb < nEdges)     out[eb]     = o[0];
        if (eb + 1 < nEdges) out[eb + 1] = o[1];
        if (eb + 2 < nEdges) out[eb + 2] = o[2];
      }
    }
  }
}

// ---- correctness-only fallback (ws too small; never expected) ---------------
__global__ void lp_naive(const float* __restrict__ z, const int* __restrict__ ei,
                         const float* __restrict__ W1, const float* __restrict__ b1,
                         const float* __restrict__ W2, const float* __restrict__ b2,
                         const float* __restrict__ W3, const float* __restrict__ b3,
                         float* __restrict__ out, int nEdges) {
  int e = blockIdx.x * 256 + threadIdx.x;
  if (e >= nEdges) return;
  int s = ei[e], d = ei[nEdges + e];
  float h1[64], h2[32];
  for (int k = 0; k < 64; ++k) {
    float a = b1[k];
    for (int i = 0; i < 128; ++i) a += z[(size_t)s * 128 + i] * W1[i * 64 + k];
    for (int i = 0; i < 128; ++i) a += z[(size_t)d * 128 + i] * W1[(128 + i) * 64 + k];
    h1[k] = a > 0.f ? a : 0.f;
  }
  for (int k = 0; k < 32; ++k) {
    float a = b2[k];
    for (int i = 0; i < 64; ++i) a += h1[i] * W2[i * 32 + k];
    h2[k] = a > 0.f ? a : 0.f;
  }
  float lg = b3[0];
  for (int i = 0; i < 32; ++i) lg += h2[i] * W3[i];
  out[e] = 1.f / (1.f + __expf(-lg));
}

extern "C" void kernel_launch(void* const* d_in, const int* in_sizes, int n_in,
                              void* d_out, int out_size, void* d_ws, size_t ws_size,
                              hipStream_t stream) {
  const float* z  = (const float*)d_in[0];
  const int* ei   = (const int*)d_in[1];
  const float* W1 = (const float*)d_in[2];
  const float* b1 = (const float*)d_in[3];
  const float* W2 = (const float*)d_in[4];
  const float* b2 = (const float*)d_in[5];
  const float* W3 = (const float*)d_in[6];
  const float* b3 = (const float*)d_in[7];
  float* out = (float*)d_out;

  const int nZ = in_sizes[0];
  const int nNodes = nZ / 128;
  const int nEdges = in_sizes[1] / 2;

  if (ws_size >= (size_t)nNodes * 128 * sizeof(unsigned short)) {
    unsigned short* uvp = (unsigned short*)d_ws;
    int nTiles = (nNodes + 15) >> 4;
    int uvGrid = (nTiles + 3) >> 2;               // 1 tile per wave
    if (uvGrid > 2048) uvGrid = 2048;
    uv_kernel<<<uvGrid, 256, 0, stream>>>(z, W1, b1, uvp, nNodes);
    lp_edge<<<2048, 256, 0, stream>>>(uvp, ei, W2, b2, W3, b3, out, nEdges);
  } else {
    lp_naive<<<(nEdges + 255) / 256, 256, 0, stream>>>(z, ei, W1, b1, W2, b2, W3, b3, out, nEdges);
  }
}

// Round 4
// 135.879 us; speedup vs baseline: 1.0921x; 1.0921x over previous
//
#include <hip/hip_runtime.h>
#include <hip/hip_bf16.h>

typedef __attribute__((ext_vector_type(8))) short short8;
typedef __attribute__((ext_vector_type(4))) float f32x4;
typedef __attribute__((ext_vector_type(2))) float f32x2;

__device__ __forceinline__ unsigned short f32_bf16(float f) {
  unsigned u = __float_as_uint(f);
  u += 0x7fffu + ((u >> 16) & 1u);  // round-to-nearest-even
  return (unsigned short)(u >> 16);
}

// HW packed f32->bf16 (RNE): dst[15:0]=bf16(lo), dst[31:16]=bf16(hi)
__device__ __forceinline__ unsigned cvt_pk_bf16(float lo, float hi) {
  unsigned r;
  asm("v_cvt_pk_bf16_f32 %0, %1, %2" : "=v"(r) : "v"(lo), "v"(hi));
  return r;
}

__device__ __forceinline__ short8 cvt8(float4 v0, float4 v1) {
  union { unsigned u[4]; short8 s; } f;
  f.u[0] = cvt_pk_bf16(v0.x, v0.y);
  f.u[1] = cvt_pk_bf16(v0.z, v0.w);
  f.u[2] = cvt_pk_bf16(v1.x, v1.y);
  f.u[3] = cvt_pk_bf16(v1.z, v1.w);
  return f.s;
}

// DPP row_shr:N add — lane 15 of each 16-lane row ends with the row sum.
template <int CTRL>
__device__ __forceinline__ float dpp_add(float x) {
  int y = __builtin_amdgcn_update_dpp(0, __float_as_int(x), CTRL, 0xf, 0xf, true);
  return x + __int_as_float(y);
}
__device__ __forceinline__ float row_sum16(float x) {
  x = dpp_add<0x118>(x);
  x = dpp_add<0x114>(x);
  x = dpp_add<0x112>(x);
  x = dpp_add<0x111>(x);
  return x;
}

// ---- fp8 UV record layout (128 B/node) --------------------------------------
// R4: UV stored as OCP e4m3 fp8 (was bf16) -> halves random-gather traffic
// (the measured ~2.8 TB/s fetch ceiling, R2 vs R3 concurrency probe) and
// halves the table (25.6 -> 12.8 MB) for ~2x better per-XCD L2 hit rate.
// Byte b of a record: b<64 (U half):   feature = 32*(b&1) + 8*(b>>4) + ((b>>1)&7)
//                     b>=64 (V half):  same formula on (b-64), feature += 64
// => a lane's 16 A-frag inputs (features q*8+j and 32+q*8+j) are the 16
// contiguous bytes at offset q*16 -> ONE 64B line per edge endpoint.

// ---- pass 1: UV[n] = fp8[ Z[n]·W1a + b1 , Z[n]·W1b ] ------------------------
// Dense GEMM M=nNodes, N=128, K=128 on 16x16x32 MFMA. W1 B-fragments staged in
// LDS with column-slot permutation chosen so lane (q,l15)'s 8 outputs are
// exactly record bytes l15*8..+7 -> one uint2 store per row.
__global__ __launch_bounds__(256, 2) void uv_kernel(
    const float* __restrict__ z, const float* __restrict__ W1,
    const float* __restrict__ b1,
    unsigned char* __restrict__ uv, int nNodes) {
  __shared__ unsigned short w1l[32 * 64 * 8];  // 32 KB
  const int tid = threadIdx.x;
  const int wv  = tid >> 6;
  const int l   = tid & 63;
  const int l15 = l & 15;
  const int q   = l >> 4;

#pragma unroll
  for (int pp = 0; pp < 8; ++pp) {
    int p = wv * 8 + pp;       // p = c*8 + t
    int c = p >> 3, t = p & 7;
    // slot(t, l15) = feature(record byte l15*8 + t)
    int n = ((l15 >= 8) ? 64 : 0) + ((t & 1) << 5) + (((l15 & 7) >> 1) << 3)
            + ((l15 & 1) << 2) + (t >> 1);
    short8 f;
#pragma unroll
    for (int j = 0; j < 8; ++j) {
      int k = c * 32 + q * 8 + j;
      int row = (n < 64) ? k : (k + 128);
      f[j] = (short)f32_bf16(W1[row * 64 + (n & 63)]);
    }
    *(short8*)(w1l + (p * 64 + l) * 8) = f;
  }
  // bias for this lane's 8 record bytes (U half only; V half gets 0)
  float b1v[8];
#pragma unroll
  for (int j = 0; j < 8; ++j) {
    int n = ((j & 1) << 5) + (((l15 & 7) >> 1) << 3) + ((l15 & 1) << 2) + (j >> 1);
    b1v[j] = (l15 < 8) ? b1[n] : 0.f;
  }
  __syncthreads();

  const int nTiles = (nNodes + 15) >> 4;
  const int stride = gridDim.x * 4;
  for (int tile = blockIdx.x * 4 + wv; tile < nTiles; tile += stride) {
    int node = tile * 16 + l15;
    node = node < nNodes ? node : nNodes - 1;
    const float* zr = z + (size_t)node * 128;
    short8 a[4];
#pragma unroll
    for (int c = 0; c < 4; ++c) {
      int off = c * 32 + q * 8;
      a[c] = cvt8(*(const float4*)(zr + off), *(const float4*)(zr + off + 4));
    }
    f32x4 acc[8];
#pragma unroll
    for (int t = 0; t < 8; ++t) { acc[t][0] = 0.f; acc[t][1] = 0.f; acc[t][2] = 0.f; acc[t][3] = 0.f; }
#pragma unroll
    for (int c = 0; c < 4; ++c)
#pragma unroll
      for (int t = 0; t < 8; ++t) {
        short8 wf = *(const short8*)(w1l + ((c * 8 + t) * 64 + l) * 8);
        acc[t] = __builtin_amdgcn_mfma_f32_16x16x32_bf16(a[c], wf, acc[t], 0, 0, 0);
      }
    // D[row=q*4+r][col=l15]; lane's 8 slot outputs = record bytes l15*8..+7
#pragma unroll
    for (int r = 0; r < 4; ++r) {
      int no = tile * 16 + q * 4 + r;
      if (no < nNodes) {
        float v0 = acc[0][r] + b1v[0], v1 = acc[1][r] + b1v[1];
        float v2 = acc[2][r] + b1v[2], v3 = acc[3][r] + b1v[3];
        float v4 = acc[4][r] + b1v[4], v5 = acc[5][r] + b1v[5];
        float v6 = acc[6][r] + b1v[6], v7 = acc[7][r] + b1v[7];
        unsigned w0 = (unsigned)__builtin_amdgcn_cvt_pk_fp8_f32(v0, v1, 0, false);
        w0 = (unsigned)__builtin_amdgcn_cvt_pk_fp8_f32(v2, v3, (int)w0, true);
        unsigned w1 = (unsigned)__builtin_amdgcn_cvt_pk_fp8_f32(v4, v5, 0, false);
        w1 = (unsigned)__builtin_amdgcn_cvt_pk_fp8_f32(v6, v7, (int)w1, true);
        uint2 pk; pk.x = w0; pk.y = w1;
        *(uint2*)(uv + (size_t)no * 128 + l15 * 8) = pk;
      }
    }
  }
}

// ---- pass 2: per-edge gather fp8 UV + relu-add + layers 2,3 + sigmoid -------
// Per edge: ONE 64B U-line (src) + ONE 64B V-line (dst). h1 computed in f32
// from fp8, packed straight into the layer-2 MFMA A-fragment layout.
__global__ __launch_bounds__(256, 8) void lp_edge(
    const unsigned char* __restrict__ uv, const int* __restrict__ ei,
    const float* __restrict__ W2, const float* __restrict__ b2,
    const float* __restrict__ W3, const float* __restrict__ b3,
    float* __restrict__ out, int nEdges) {
  const int tid = threadIdx.x;
  const int wv  = tid >> 6;
  const int l   = tid & 63;
  const int l15 = l & 15;
  const int q   = l >> 4;

  short8 w2f[2][2];
#pragma unroll
  for (int c = 0; c < 2; ++c)
#pragma unroll
    for (int t = 0; t < 2; ++t) {
      short8 f;
#pragma unroll
      for (int j = 0; j < 8; ++j)
        f[j] = (short)f32_bf16(W2[(c * 32 + q * 8 + j) * 32 + (t * 16 + l15)]);
      w2f[c][t] = f;
    }
  float bb2[2];
#pragma unroll
  for (int t = 0; t < 2; ++t) bb2[t] = b2[t * 16 + l15];
  const float w3a = W3[l15], w3b = W3[16 + l15], b3v = b3[0];

  const unsigned q16 = (unsigned)q * 16u;

  const int nIter = (nEdges + 15) >> 4;
  const int stride = gridDim.x * 4;
  const int it0 = blockIdx.x * 4 + wv;

  // index prefetch one iteration ahead
  int e0 = it0 * 16 + l15; e0 = e0 < nEdges ? e0 : nEdges - 1;
  int cS = __builtin_nontemporal_load(ei + e0);
  int cD = __builtin_nontemporal_load(ei + nEdges + e0);

  for (int iter = it0; iter < nIter; iter += stride) {
    unsigned offU = ((unsigned)cS << 7) + q16;          // U half: bytes 0..63
    unsigned offV = ((unsigned)cD << 7) + 64u + q16;    // V half: bytes 64..127
    uint4 uu = *(const uint4*)(uv + offU);
    uint4 vv = *(const uint4*)(uv + offV);

    int nit = iter + stride;
    if (nit < nIter) {
      int e = nit * 16 + l15;
      e = e < nEdges ? e : nEdges - 1;
      cS = __builtin_nontemporal_load(ei + e);
      cD = __builtin_nontemporal_load(ei + nEdges + e);
    }

    // unpack fp8 pairs (f0_j, f1_j per byte-pair), add U+V, relu, pack bf16
    union { unsigned u[4]; short8 s; } f0, f1;
    unsigned uw[4] = {uu.x, uu.y, uu.z, uu.w};
    unsigned vw[4] = {vv.x, vv.y, vv.z, vv.w};
#pragma unroll
    for (int k = 0; k < 4; ++k) {
      f32x2 ua = __builtin_amdgcn_cvt_pk_f32_fp8((int)uw[k], false);
      f32x2 ub = __builtin_amdgcn_cvt_pk_f32_fp8((int)uw[k], true);
      f32x2 va = __builtin_amdgcn_cvt_pk_f32_fp8((int)vw[k], false);
      f32x2 vb = __builtin_amdgcn_cvt_pk_f32_fp8((int)vw[k], true);
      float s0a = ua.x + va.x; s0a = s0a > 0.f ? s0a : 0.f;  // f0_{2k}
      float s1a = ua.y + va.y; s1a = s1a > 0.f ? s1a : 0.f;  // f1_{2k}
      float s0b = ub.x + vb.x; s0b = s0b > 0.f ? s0b : 0.f;  // f0_{2k+1}
      float s1b = ub.y + vb.y; s1b = s1b > 0.f ? s1b : 0.f;  // f1_{2k+1}
      f0.u[k] = cvt_pk_bf16(s0a, s0b);
      f1.u[k] = cvt_pk_bf16(s1a, s1b);
    }

    // layer 2: [16,64] @ [64,32] + b2
    f32x4 acc2[2];
#pragma unroll
    for (int t = 0; t < 2; ++t) {
      acc2[t][0] = bb2[t]; acc2[t][1] = bb2[t]; acc2[t][2] = bb2[t]; acc2[t][3] = bb2[t];
    }
#pragma unroll
    for (int t = 0; t < 2; ++t) {
      acc2[t] = __builtin_amdgcn_mfma_f32_16x16x32_bf16(f0.s, w2f[0][t], acc2[t], 0, 0, 0);
      acc2[t] = __builtin_amdgcn_mfma_f32_16x16x32_bf16(f1.s, w2f[1][t], acc2[t], 0, 0, 0);
    }

    // layer 3: per-lane partial, DPP row-sum
    float p[4];
#pragma unroll
    for (int r = 0; r < 4; ++r) {
      float h0 = acc2[0][r]; h0 = h0 > 0.f ? h0 : 0.f;
      float h1v = acc2[1][r]; h1v = h1v > 0.f ? h1v : 0.f;
      p[r] = row_sum16(h0 * w3a + h1v * w3b);
    }

    if (l15 == 15) {
      int eb = iter * 16 + q * 4;
      f32x4 o;
      o[0] = 1.f / (1.f + __expf(-(p[0] + b3v)));
      o[1] = 1.f / (1.f + __expf(-(p[1] + b3v)));
      o[2] = 1.f / (1.f + __expf(-(p[2] + b3v)));
      o[3] = 1.f / (1.f + __expf(-(p[3] + b3v)));
      if (eb + 3 < nEdges) {
        __builtin_nontemporal_store(o, (f32x4*)(out + eb));
      } else {
        if (eb < nEdges)     out[eb]     = o[0];
        if (eb + 1 < nEdges) out[eb + 1] = o[1];
        if (eb + 2 < nEdges) out[eb + 2] = o[2];
      }
    }
  }
}

// ---- correctness-only fallback (ws too small; never expected) ---------------
__global__ void lp_naive(const float* __restrict__ z, const int* __restrict__ ei,
                         const float* __restrict__ W1, const float* __restrict__ b1,
                         const float* __restrict__ W2, const float* __restrict__ b2,
                         const float* __restrict__ W3, const float* __restrict__ b3,
                         float* __restrict__ out, int nEdges) {
  int e = blockIdx.x * 256 + threadIdx.x;
  if (e >= nEdges) return;
  int s = ei[e], d = ei[nEdges + e];
  float h1[64], h2[32];
  for (int k = 0; k < 64; ++k) {
    float a = b1[k];
    for (int i = 0; i < 128; ++i) a += z[(size_t)s * 128 + i] * W1[i * 64 + k];
    for (int i = 0; i < 128; ++i) a += z[(size_t)d * 128 + i] * W1[(128 + i) * 64 + k];
    h1[k] = a > 0.f ? a : 0.f;
  }
  for (int k = 0; k < 32; ++k) {
    float a = b2[k];
    for (int i = 0; i < 64; ++i) a += h1[i] * W2[i * 32 + k];
    h2[k] = a > 0.f ? a : 0.f;
  }
  float lg = b3[0];
  for (int i = 0; i < 32; ++i) lg += h2[i] * W3[i];
  out[e] = 1.f / (1.f + __expf(-lg));
}

extern "C" void kernel_launch(void* const* d_in, const int* in_sizes, int n_in,
                              void* d_out, int out_size, void* d_ws, size_t ws_size,
                              hipStream_t stream) {
  const float* z  = (const float*)d_in[0];
  const int* ei   = (const int*)d_in[1];
  const float* W1 = (const float*)d_in[2];
  const float* b1 = (const float*)d_in[3];
  const float* W2 = (const float*)d_in[4];
  const float* b2 = (const float*)d_in[5];
  const float* W3 = (const float*)d_in[6];
  const float* b3 = (const float*)d_in[7];
  float* out = (float*)d_out;

  const int nZ = in_sizes[0];
  const int nNodes = nZ / 128;
  const int nEdges = in_sizes[1] / 2;

  if (ws_size >= (size_t)nNodes * 128) {
    unsigned char* uvp = (unsigned char*)d_ws;
    int nTiles = (nNodes + 15) >> 4;
    int uvGrid = (nTiles + 3) >> 2;               // 1 tile per wave
    if (uvGrid > 2048) uvGrid = 2048;
    uv_kernel<<<uvGrid, 256, 0, stream>>>(z, W1, b1, uvp, nNodes);
    lp_edge<<<2048, 256, 0, stream>>>(uvp, ei, W2, b2, W3, b3, out, nEdges);
  } else {
    lp_naive<<<(nEdges + 255) / 256, 256, 0, stream>>>(z, ei, W1, b1, W2, b2, W3, b3, out, nEdges);
  }
}